// Round 6
// baseline (387.079 us; speedup 1.0000x reference)
//
#include <hip/hip_runtime.h>
#include <stdint.h>

typedef float v4f __attribute__((ext_vector_type(4)));
typedef int v8i __attribute__((ext_vector_type(8)));

#define FP8_DENOM 358.4f  // FP8_MAX(448) * SCALE_MARGIN(0.8)

// ---------- helpers ----------

__device__ __forceinline__ unsigned pack4_fp8(float a, float b, float c, float d) {
  int v = 0;
  v = __builtin_amdgcn_cvt_pk_fp8_f32(a, b, v, false);  // bytes 0,1
  v = __builtin_amdgcn_cvt_pk_fp8_f32(c, d, v, true);   // bytes 2,3
  return (unsigned)v;
}

__device__ __forceinline__ void gload_lds16(const void* g, void* l) {
  __builtin_amdgcn_global_load_lds(
      (const __attribute__((address_space(1))) uint32_t*)(uintptr_t)g,
      (__attribute__((address_space(3))) uint32_t*)(uint32_t)(uintptr_t)l,
      16, 0, 0);
}

// ---------- stage 1: per-block amax -> single atomicMax (FROZEN r3) ------

__global__ void __launch_bounds__(256) amax_part(const float4* __restrict__ x,
                                                 const float4* __restrict__ w,
                                                 unsigned* __restrict__ amax) {
  const int b = blockIdx.x, t = threadIdx.x;
  const int isw = (b >= 1024) ? 1 : 0;
  const float4* p = isw ? w : x;
  const long base = (long)(isw ? (b - 1024) : b) * 4096;
  float m0 = 0.f, m1 = 0.f, m2 = 0.f, m3 = 0.f;
#pragma unroll
  for (int j = 0; j < 4; ++j) {
    float4 v0 = p[base + (j * 4 + 0) * 256 + t];
    float4 v1 = p[base + (j * 4 + 1) * 256 + t];
    float4 v2 = p[base + (j * 4 + 2) * 256 + t];
    float4 v3 = p[base + (j * 4 + 3) * 256 + t];
    m0 = fmaxf(m0, fmaxf(fmaxf(fabsf(v0.x), fabsf(v0.y)), fmaxf(fabsf(v0.z), fabsf(v0.w))));
    m1 = fmaxf(m1, fmaxf(fmaxf(fabsf(v1.x), fabsf(v1.y)), fmaxf(fabsf(v1.z), fabsf(v1.w))));
    m2 = fmaxf(m2, fmaxf(fmaxf(fabsf(v2.x), fabsf(v2.y)), fmaxf(fabsf(v2.z), fabsf(v2.w))));
    m3 = fmaxf(m3, fmaxf(fmaxf(fabsf(v3.x), fabsf(v3.y)), fmaxf(fabsf(v3.z), fabsf(v3.w))));
  }
  float m = fmaxf(fmaxf(m0, m1), fmaxf(m2, m3));
#pragma unroll
  for (int off = 32; off > 0; off >>= 1)
    m = fmaxf(m, __shfl_down(m, off, 64));
  __shared__ float red[4];
  const int lane = t & 63, wvid = t >> 6;
  if (lane == 0) red[wvid] = m;
  __syncthreads();
  if (t == 0)
    atomicMax(amax + isw,
              __float_as_uint(fmaxf(fmaxf(red[0], red[1]), fmaxf(red[2], red[3]))));
}

// ---------- stage 2: fused quantize (FROZEN r3) ----------

__global__ void __launch_bounds__(256) quant2_kernel(
    const float4* __restrict__ x, unsigned* __restrict__ xq,
    const float4* __restrict__ w, unsigned* __restrict__ wq,
    const unsigned* __restrict__ amax) {
  const int t = threadIdx.x;
  const int isw = ((int)blockIdx.x >= 4096) ? 1 : 0;
  const float ax = __uint_as_float(amax[0]);
  const float aw = __uint_as_float(amax[1]);
  const float s = (isw ? fmaxf(ax, aw) : ax) / FP8_DENOM;
  const float rs = 1.0f / s;
  const float4* in = isw ? w : x;
  unsigned* outq = isw ? wq : xq;
  const long base = (long)(isw ? ((int)blockIdx.x - 4096) : (int)blockIdx.x) * 1024;
#pragma unroll
  for (int j = 0; j < 4; ++j) {
    float4 v = in[base + j * 256 + t];
    outq[base + j * 256 + t] = pack4_fp8(v.x * rs, v.y * rs, v.z * rs, v.w * rs);
  }
}

// ---------- MX-scaled fp8 GEMM, faithful m201 8-phase port ----------
// M=8192 N=2048 K=2048. 256x256 tile, 512 thr (8 waves 2x4, 128x64/wave),
// BK=128 (byte-identical geometry to m201's bf16 BK=64: 128B rows, 16KB
// half-tiles, 8 gloads/thread/K-tile). r0-r5 post-mortem: every variant put
// ds_reads AFTER a barrier and consumed them immediately -> LDS round-trip
// naked on the critical path, MfmaUtil pinned at ~26%. m201's phase anatomy
// (62% MfmaUtil at this exact occupancy/LDS config): reads issued BEFORE the
// phase barrier, consumed ONE PHASE LATER from registers; 2 barriers/phase.
//   ph0: stage(u+1)->buf^1 | read a23 | bar | MFMA rows01 (regs) | bar
//   ph1:                     read a45 | bar | MFMA rows23        | bar
//   ph2:                     read a67 | bar | MFMA rows45        | bar
//   ph3: vmcnt(0)+bar [u+1 visible, 3-phase flight ~1000cy >> latency]
//        read a01/b0123 of u+1 (buf^1) | MFMA rows67 | bar
// A row-pairs double-buffered in regs (aE/aO alternate per phase, pattern is
// tile-invariant); B double-buffered across tiles via 2x loop unroll (static
// indexing, rule 20). No explicit lgkm asm: plain C++ loads -> compiler emits
// exact counted lgkmcnt (m97 evidence). Regs: acc128+aE8+aO8+bC32+bN32+~25.

__global__ void __launch_bounds__(512, 2) gemm_mx(
    const uint8_t* __restrict__ Aq, const uint8_t* __restrict__ Bq,
    const float* __restrict__ bias, float* __restrict__ out,
    const unsigned* __restrict__ amax) {
  constexpr int K = 2048, N = 2048, BK = 128, ITERS = K / BK;
  __shared__ alignas(16) uint8_t sA[2][256 * BK];  // 2 x 32 KB
  __shared__ alignas(16) uint8_t sB[2][256 * BK];  // 2 x 32 KB

  const int tid = threadIdx.x;
  const int lane = tid & 63;
  const int wid = tid >> 6;               // 0..7
  const int wy = wid >> 2, wx = wid & 3;  // 2x4 waves -> 128x64 per wave

  // T1: bijective XCD-chunk swizzle (256 blocks, 256%8==0). r3-verified:
  // FETCH 67.6 -> 24.7 MB.
  const int orig = (int)blockIdx.y * (int)gridDim.x + (int)blockIdx.x;
  const int wg = (orig & 7) * 32 + (orig >> 3);
  const long tileM = (long)(wg >> 3) * 256;
  const long tileN = (long)(wg & 7) * 256;

  v4f acc[8][4];
#pragma unroll
  for (int i = 0; i < 8; ++i)
#pragma unroll
    for (int j = 0; j < 4; ++j) acc[i][j] = (v4f)(0.f);

  // staging: thread t -> row srow = t>>3 (+ s*64), phys chunk t&7,
  // source logical chunk = (t&7) ^ (srow&7)
  const int srow = tid >> 3;
  const int schunk = (tid & 7) ^ (srow & 7);
  const uint8_t* gA = Aq + (tileM + srow) * K + schunk * 16;
  const uint8_t* gB = Bq + (tileN + srow) * K + schunk * 16;

  const int q = lane >> 4;     // k-block: lane holds k = q*32 .. q*32+31
  const int mrow = lane & 15;  // row within 16x16 tile
  const int sw = mrow & 7;
  const int aoff0 = (wy * 128 + mrow) * BK + 16 * ((2 * q) ^ sw);
  const int aoff1 = (wy * 128 + mrow) * BK + 16 * ((2 * q + 1) ^ sw);
  const int boff0 = (wx * 64 + mrow) * BK + 16 * ((2 * q) ^ sw);
  const int boff1 = (wx * 64 + mrow) * BK + 16 * ((2 * q + 1) ^ sw);

  auto stage = [&](int buf, int k0) {
#pragma unroll
    for (int s = 0; s < 4; ++s) {
      gload_lds16(gA + (long)s * 64 * K + k0, &sA[buf][s * 8192 + tid * 16]);
      gload_lds16(gB + (long)s * 64 * K + k0, &sB[buf][s * 8192 + tid * 16]);
    }
  };

  union Frag { v8i v; uint4 h[2]; };
  Frag aE[2], aO[2], bC[4], bN[4];

#define LD_A2(bufA, d, r0i)                                          \
  do {                                                               \
    d[0].h[0] = *(const uint4*)((bufA) + aoff0 + (r0i + 0) * 16 * BK); \
    d[0].h[1] = *(const uint4*)((bufA) + aoff1 + (r0i + 0) * 16 * BK); \
    d[1].h[0] = *(const uint4*)((bufA) + aoff0 + (r0i + 1) * 16 * BK); \
    d[1].h[1] = *(const uint4*)((bufA) + aoff1 + (r0i + 1) * 16 * BK); \
  } while (0)

#define LD_B4(bufB, d)                                               \
  do {                                                               \
    d[0].h[0] = *(const uint4*)((bufB) + boff0 + 0 * 16 * BK);       \
    d[0].h[1] = *(const uint4*)((bufB) + boff1 + 0 * 16 * BK);       \
    d[1].h[0] = *(const uint4*)((bufB) + boff0 + 1 * 16 * BK);       \
    d[1].h[1] = *(const uint4*)((bufB) + boff1 + 1 * 16 * BK);       \
    d[2].h[0] = *(const uint4*)((bufB) + boff0 + 2 * 16 * BK);       \
    d[2].h[1] = *(const uint4*)((bufB) + boff1 + 2 * 16 * BK);       \
    d[3].h[0] = *(const uint4*)((bufB) + boff0 + 3 * 16 * BK);       \
    d[3].h[1] = *(const uint4*)((bufB) + boff1 + 3 * 16 * BK);       \
  } while (0)

#define MFMA2(r0i, aa, bb)                                           \
  do {                                                               \
    __builtin_amdgcn_s_setprio(1);                                   \
    _Pragma("unroll") for (int j = 0; j < 4; ++j)                    \
        acc[r0i + 0][j] = __builtin_amdgcn_mfma_scale_f32_16x16x128_f8f6f4( \
            aa[0].v, bb[j].v, acc[r0i + 0][j], 0, 0, 0, 0x7F7F7F7F, 0, 0x7F7F7F7F); \
    _Pragma("unroll") for (int j = 0; j < 4; ++j)                    \
        acc[r0i + 1][j] = __builtin_amdgcn_mfma_scale_f32_16x16x128_f8f6f4( \
            aa[1].v, bb[j].v, acc[r0i + 1][j], 0, 0, 0, 0x7F7F7F7F, 0, 0x7F7F7F7F); \
    __builtin_amdgcn_s_setprio(0);                                   \
  } while (0)

#define BAR()                          \
  do {                                 \
    __builtin_amdgcn_s_barrier();      \
    __builtin_amdgcn_sched_barrier(0); \
  } while (0)

  // TILE_BODY: parity P (tile u in sA/sB[P]); BC = this tile's B frags,
  // BN = next tile's B frags (filled in ph3).
#define TILE_BODY(P, u, BC, BN)                                      \
  do {                                                               \
    const uint8_t* bA = sA[P];                                       \
    const bool pf = (u) + 1 < ITERS;                                 \
    /* ph0 */                                                        \
    if (pf) stage((P) ^ 1, ((u) + 1) * BK);                          \
    LD_A2(bA, aO, 2);                                                \
    BAR();                                                           \
    MFMA2(0, aE, BC);                                                \
    BAR();                                                           \
    /* ph1 */                                                        \
    LD_A2(bA, aE, 4);                                                \
    BAR();                                                           \
    MFMA2(2, aO, BC);                                                \
    BAR();                                                           \
    /* ph2 */                                                        \
    LD_A2(bA, aO, 6);                                                \
    BAR();                                                           \
    MFMA2(4, aE, BC);                                                \
    BAR();                                                           \
    /* ph3: next tile visible (3-phase flight), read its first subtiles */ \
    asm volatile("s_waitcnt vmcnt(0)" ::: "memory");                 \
    BAR();                                                           \
    if (pf) {                                                        \
      LD_A2(sA[(P) ^ 1], aE, 0);                                     \
      LD_B4(sB[(P) ^ 1], BN);                                        \
    }                                                                \
    MFMA2(6, aO, BC);                                                \
    BAR();                                                           \
  } while (0)

  // prologue: tile 0 staged, first register subtiles loaded
  stage(0, 0);
  asm volatile("s_waitcnt vmcnt(0)" ::: "memory");
  __builtin_amdgcn_s_barrier();
  __builtin_amdgcn_sched_barrier(0);
  LD_B4(sB[0], bC);
  LD_A2(sA[0], aE, 0);

  for (int u = 0; u < ITERS; u += 2) {
    TILE_BODY(0, u, bC, bN);
    TILE_BODY(1, u + 1, bN, bC);
  }

  // epilogue: C/D layout col=lane&15, row=(lane>>4)*4+reg
  const float ax = __uint_as_float(amax[0]);
  const float aw = __uint_as_float(amax[1]);
  const float scale = (ax / FP8_DENOM) * (fmaxf(ax, aw) / FP8_DENOM);
#pragma unroll
  for (int j = 0; j < 4; ++j) {
    const long col = tileN + wx * 64 + j * 16 + mrow;
    const float bv = bias[col];
#pragma unroll
    for (int i = 0; i < 8; ++i) {
      const long row = tileM + wy * 128 + i * 16 + q * 4;
#pragma unroll
      for (int r = 0; r < 4; ++r)
        out[(row + r) * N + col] = acc[i][j][r] * scale + bv;
    }
  }
#undef TILE_BODY
#undef BAR
#undef MFMA2
#undef LD_B4
#undef LD_A2
}

// ---------- launch ----------

extern "C" void kernel_launch(void* const* d_in, const int* in_sizes, int n_in,
                              void* d_out, int out_size, void* d_ws, size_t ws_size,
                              hipStream_t stream) {
  const float* x = (const float*)d_in[0];     // [4,2048,2048] -> [8192,2048]
  const float* w = (const float*)d_in[1];     // [2048,2048]
  const float* bias = (const float*)d_in[2];  // [2048]
  float* out = (float*)d_out;                 // [8192,2048] fp32

  const int M = 8192, N = 2048, K = 2048;
  const long nx = (long)M * K;

  unsigned* amax = (unsigned*)d_ws;
  uint8_t* xq = (uint8_t*)d_ws + 8192;
  uint8_t* wq = xq + nx;

  hipMemsetAsync(amax, 0, 8, stream);  // graph-capturable
  amax_part<<<1280, 256, 0, stream>>>((const float4*)x, (const float4*)w, amax);
  quant2_kernel<<<5120, 256, 0, stream>>>((const float4*)x, (unsigned*)xq,
                                          (const float4*)w, (unsigned*)wq, amax);
  gemm_mx<<<dim3(N / 256, M / 256), 512, 0, stream>>>(xq, wq, bias, out, amax);
}

// Round 8
// 249.836 us; speedup vs baseline: 1.5493x; 1.5493x over previous
//
#include <hip/hip_runtime.h>
#include <stdint.h>

typedef float v4f __attribute__((ext_vector_type(4)));
typedef int v8i __attribute__((ext_vector_type(8)));

#define FP8_DENOM 358.4f  // FP8_MAX(448) * SCALE_MARGIN(0.8)

// ---------- helpers ----------

__device__ __forceinline__ unsigned pack4_fp8(float a, float b, float c, float d) {
  // v_cvt_pk_fp8_f32: RNE, saturating (values <=358.4 by construction)
  int v = 0;
  v = __builtin_amdgcn_cvt_pk_fp8_f32(a, b, v, false);  // bytes 0,1
  v = __builtin_amdgcn_cvt_pk_fp8_f32(c, d, v, true);   // bytes 2,3
  return (unsigned)v;
}

__device__ __forceinline__ void gload_lds16(const void* g, void* l) {
  // 16B-wide async global->LDS. LDS dest must be wave-uniform base + lane*16.
  __builtin_amdgcn_global_load_lds(
      (const __attribute__((address_space(1))) uint32_t*)(uintptr_t)g,
      (__attribute__((address_space(3))) uint32_t*)(uint32_t)(uintptr_t)l,
      16, 0, 0);
}

__device__ __forceinline__ float amax4(float m, float4 v) {
  return fmaxf(m, fmaxf(fmaxf(fabsf(v.x), fabsf(v.y)), fmaxf(fabsf(v.z), fabsf(v.w))));
}

// ---------- fused amax + quantize (persistent, software grid barrier) ------
// r7 post-mortem: hipLaunchCooperativeKernel never executed under the
// harness's graph capture (out==bias==0 -> scale==0 -> amax never written).
// Same fusion, no coop API: 512 blocks x 256 thr (~60 VGPR, no LDS ->
// >=8 blocks/CU capacity, 512 = 2/CU guaranteed co-resident, 4x margin).
// pass1 local amax -> device-scope atomicMax -> threadfence -> release
// fetch_add(counter) -> t0 spins (agent acquire) until counter==512 ->
// __syncthreads -> agent-scope loads of amax -> pass2 quantize (x/w re-read
// is L3-warm: 80MB << 256MB L3). sync[0]=amax_x, [1]=amax_w, [2]=counter;
// zeroed by the captured 16B hipMemsetAsync each replay.

__global__ void __launch_bounds__(256) amax_quant(
    const float4* __restrict__ x, unsigned* __restrict__ xq,
    const float4* __restrict__ w, unsigned* __restrict__ wq,
    unsigned* __restrict__ sync) {
  constexpr int NX4 = 4194304;  // 8192*2048/4
  constexpr int NW4 = 1048576;  // 2048*2048/4
  constexpr int GRID = 512;
  constexpr int GSIZE = GRID * 256;
  const int t = threadIdx.x;
  const int gtid = (int)blockIdx.x * 256 + t;

  // ---- pass 1: amax (x: 32 iters, w: 8 iters; 1KB/wave-instr coalesced) ----
  float mx = 0.f, mw = 0.f;
#pragma unroll 8
  for (int j = 0; j < NX4 / GSIZE; ++j) mx = amax4(mx, x[gtid + j * GSIZE]);
#pragma unroll 8
  for (int j = 0; j < NW4 / GSIZE; ++j) mw = amax4(mw, w[gtid + j * GSIZE]);

#pragma unroll
  for (int off = 32; off > 0; off >>= 1) {
    mx = fmaxf(mx, __shfl_down(mx, off, 64));
    mw = fmaxf(mw, __shfl_down(mw, off, 64));
  }
  __shared__ float rx[4], rw[4];
  const int lane = t & 63, wvid = t >> 6;
  if (lane == 0) { rx[wvid] = mx; rw[wvid] = mw; }
  __syncthreads();
  if (t == 0) {
    // uint-bit max == float max for non-negative floats; device scope default
    atomicMax(sync + 0, __float_as_uint(fmaxf(fmaxf(rx[0], rx[1]), fmaxf(rx[2], rx[3]))));
    atomicMax(sync + 1, __float_as_uint(fmaxf(fmaxf(rw[0], rw[1]), fmaxf(rw[2], rw[3]))));
    __threadfence();  // amax updates visible before counter increment
    __hip_atomic_fetch_add(sync + 2, 1u, __ATOMIC_ACQ_REL, __HIP_MEMORY_SCOPE_AGENT);
    // ---- software grid barrier (all 512 blocks co-resident) ----
    while (__hip_atomic_load(sync + 2, __ATOMIC_ACQUIRE, __HIP_MEMORY_SCOPE_AGENT) < GRID)
      __builtin_amdgcn_s_sleep(2);
  }
  __syncthreads();

  // agent-scope loads: cross-XCD coherent read of the final maxima
  const float ax = __uint_as_float(
      __hip_atomic_load(sync + 0, __ATOMIC_ACQUIRE, __HIP_MEMORY_SCOPE_AGENT));
  const float aw = __uint_as_float(
      __hip_atomic_load(sync + 1, __ATOMIC_ACQUIRE, __HIP_MEMORY_SCOPE_AGENT));
  const float rsx = 1.0f / (ax / FP8_DENOM);
  const float rsw = 1.0f / (fmaxf(ax, aw) / FP8_DENOM);  // shared amax history max

  // ---- pass 2: quantize (reads L3-warm) ----
#pragma unroll 4
  for (int j = 0; j < NX4 / GSIZE; ++j) {
    float4 v = x[gtid + j * GSIZE];
    xq[gtid + j * GSIZE] = pack4_fp8(v.x * rsx, v.y * rsx, v.z * rsx, v.w * rsx);
  }
#pragma unroll 4
  for (int j = 0; j < NW4 / GSIZE; ++j) {
    float4 v = w[gtid + j * GSIZE];
    wq[gtid + j * GSIZE] = pack4_fp8(v.x * rsw, v.y * rsw, v.z * rsw, v.w * rsw);
  }
}

// ---------- MX-scaled fp8 GEMM (round-0 structure: best measured, 47-49us) -
// M=8192 N=2048 K=2048. 128x128x128 tile, 4 waves (2x2), 16x16x128 mfma_scale
// with unit e8m0 scales. 2x32KB LDS double-buffer -> 64KB -> 2 blocks/CU;
// the co-resident second block's waves cover the barrier drain (r0-r6
// established this beats every 1-block/CU phase-pipelined variant).
// Only change vs round-0: epilogue scale computed inline from amax bits
// (scale_reduce kernel eliminated), bit-identical float expressions.

__global__ void __launch_bounds__(256) gemm_mx(
    const uint8_t* __restrict__ Aq, const uint8_t* __restrict__ Bq,
    const float* __restrict__ bias, float* __restrict__ out,
    const unsigned* __restrict__ amax) {
  constexpr int K = 2048, N = 2048, BK = 128, ITERS = K / BK;
  __shared__ alignas(16) uint8_t sA[2][128 * BK];
  __shared__ alignas(16) uint8_t sB[2][128 * BK];

  const int tid = threadIdx.x;
  const int lane = tid & 63;
  const int wid = tid >> 6;
  const int wy = wid >> 1, wx = wid & 1;  // 2x2 waves -> 64x64 per wave
  const long tileM = (long)blockIdx.y * 128;
  const long tileN = (long)blockIdx.x * 128;

  v4f acc[4][4];
#pragma unroll
  for (int i = 0; i < 4; ++i)
#pragma unroll
    for (int j = 0; j < 4; ++j) acc[i][j] = (v4f)(0.f);

  // staging: thread t -> row srow = t>>3 (+ s*32), phys chunk t&7,
  // source logical chunk = (t&7) ^ (srow&7)  (row&7 invariant across s)
  const int srow = tid >> 3;
  const int schunk = (tid & 7) ^ (srow & 7);
  const uint8_t* gA = Aq + (tileM + srow) * K + schunk * 16;
  const uint8_t* gB = Bq + (tileN + srow) * K + schunk * 16;

  const int q = lane >> 4;     // k-block: lane holds k = q*32 .. q*32+31
  const int mrow = lane & 15;  // row within 16x16 tile

  // fragment LDS offsets (loop-invariant): logical chunks 2q,2q+1 of row r
  int aoff[4][2], boff[4][2];
#pragma unroll
  for (int i = 0; i < 4; ++i) {
    const int rA = wy * 64 + i * 16 + mrow, swA = rA & 7;
    aoff[i][0] = rA * 128 + 16 * ((2 * q) ^ swA);
    aoff[i][1] = rA * 128 + 16 * ((2 * q + 1) ^ swA);
    const int rB = wx * 64 + i * 16 + mrow, swB = rB & 7;
    boff[i][0] = rB * 128 + 16 * ((2 * q) ^ swB);
    boff[i][1] = rB * 128 + 16 * ((2 * q + 1) ^ swB);
  }

  auto stage = [&](int buf, int k0) {
#pragma unroll
    for (int s = 0; s < 4; ++s) {
      gload_lds16(gA + (long)s * 32 * K + k0, &sA[buf][s * 4096 + tid * 16]);
      gload_lds16(gB + (long)s * 32 * K + k0, &sB[buf][s * 4096 + tid * 16]);
    }
  };

  stage(0, 0);
  for (int it = 0; it < ITERS; ++it) {
    __syncthreads();  // drains staging(it) — overlapped with prev iter's MFMAs
    if (it + 1 < ITERS) stage((it + 1) & 1, (it + 1) * BK);  // async prefetch

    const uint8_t* bufA = sA[it & 1];
    const uint8_t* bufB = sB[it & 1];
    union Frag { v8i v; uint4 h[2]; };
    Frag a[4], b[4];
#pragma unroll
    for (int i = 0; i < 4; ++i) {
      a[i].h[0] = *(const uint4*)(bufA + aoff[i][0]);
      a[i].h[1] = *(const uint4*)(bufA + aoff[i][1]);
      b[i].h[0] = *(const uint4*)(bufB + boff[i][0]);
      b[i].h[1] = *(const uint4*)(bufB + boff[i][1]);
    }
#pragma unroll
    for (int i = 0; i < 4; ++i)
#pragma unroll
      for (int j = 0; j < 4; ++j)
        acc[i][j] = __builtin_amdgcn_mfma_scale_f32_16x16x128_f8f6f4(
            a[i].v, b[j].v, acc[i][j], /*cbsz=fp8*/ 0, /*blgp=fp8*/ 0,
            /*opsel_a*/ 0, 0x7F7F7F7F, /*opsel_b*/ 0, 0x7F7F7F7F);  // e8m0 127 = x1.0
  }

  // epilogue: C/D layout col=lane&15, row=(lane>>4)*4+reg (shape-determined)
  const float ax = __uint_as_float(amax[0]);
  const float aw = __uint_as_float(amax[1]);
  const float scale = (ax / FP8_DENOM) * (fmaxf(ax, aw) / FP8_DENOM);
#pragma unroll
  for (int j = 0; j < 4; ++j) {
    const long col = tileN + wx * 64 + j * 16 + mrow;
    const float bv = bias[col];
#pragma unroll
    for (int i = 0; i < 4; ++i) {
      const long row = tileM + wy * 64 + i * 16 + q * 4;
#pragma unroll
      for (int r = 0; r < 4; ++r)
        out[(row + r) * N + col] = acc[i][j][r] * scale + bv;
    }
  }
}

// ---------- launch ----------

extern "C" void kernel_launch(void* const* d_in, const int* in_sizes, int n_in,
                              void* d_out, int out_size, void* d_ws, size_t ws_size,
                              hipStream_t stream) {
  const float* x = (const float*)d_in[0];     // [4,2048,2048] -> [8192,2048]
  const float* w = (const float*)d_in[1];     // [2048,2048]
  const float* bias = (const float*)d_in[2];  // [2048]
  float* out = (float*)d_out;                 // [8192,2048] fp32

  const int M = 8192, N = 2048, K = 2048;
  const long nx = (long)M * K;

  // ws layout: [0,16): amax_x, amax_w, barrier counter, pad;
  // [8192, 8192+nx): xq codes; then wq codes.
  unsigned* syncw = (unsigned*)d_ws;
  uint8_t* xq = (uint8_t*)d_ws + 8192;
  uint8_t* wq = xq + nx;

  hipMemsetAsync(syncw, 0, 16, stream);  // graph-capturable

  amax_quant<<<512, 256, 0, stream>>>((const float4*)x, (unsigned*)xq,
                                      (const float4*)w, (unsigned*)wq, syncw);
  gemm_mx<<<dim3(N / 128, M / 128), 256, 0, stream>>>(xq, wq, bias, out, syncw);
}